// Round 5
// baseline (118.644 us; speedup 1.0000x reference)
//
#include <hip/hip_runtime.h>

#define N_NODES 100000
#define N_EDGES 1000000
#define HIDDEN 64

// ---- range-pass geometry ----
#define N_RANGES 7
#define C_RANGE 14336                   // 7*14336 = 100352 >= 100000; bins = 57,344 B LDS
#define N_SLICES 64
#define ES ((N_EDGES + N_SLICES - 1) / N_SLICES)   // 15625 edges per slice
#define A_THREADS 512

// kc[0..3]=(W1@Wout)[k], kc[4]=b1.Wout, kc[5..8]=W1[k][0], kc[9..12]=W1[k][1],
// kc[13]=b1[0], kc[14]=b1[1], kc[15]=Wout[0], kc[16]=Wout[1], kc[17]=bout[0]
__device__ __forceinline__ void compute_consts(
    const float* __restrict__ W1, const float* __restrict__ b1,
    const float* __restrict__ Wout, const float* __restrict__ bout,
    float* kc, int tid) {
    if (tid < 64) {
        float wj = Wout[tid];
        float p0 = W1[0 * HIDDEN + tid] * wj;
        float p1 = W1[1 * HIDDEN + tid] * wj;
        float p2 = W1[2 * HIDDEN + tid] * wj;
        float p3 = W1[3 * HIDDEN + tid] * wj;
        float pb = b1[tid] * wj;
        #pragma unroll
        for (int off = 32; off > 0; off >>= 1) {
            p0 += __shfl_down(p0, off);
            p1 += __shfl_down(p1, off);
            p2 += __shfl_down(p2, off);
            p3 += __shfl_down(p3, off);
            pb += __shfl_down(pb, off);
        }
        if (tid < 4) {
            kc[5 + tid] = W1[tid * HIDDEN + 0];
            kc[9 + tid] = W1[tid * HIDDEN + 1];
        }
        if (tid == 0) {
            kc[0] = p0; kc[1] = p1; kc[2] = p2; kc[3] = p3; kc[4] = pb;
            kc[13] = b1[0]; kc[14] = b1[1];
            kc[15] = Wout[0]; kc[16] = Wout[1];
            kc[17] = bout[0];
        }
    }
}

// ---- Kernel A: block (r,s) = range r, edge-slice s. LDS bins for range r,
// filtered accumulation, coalesced flush to part[blockIdx][C_RANGE].
// No global atomics; no scattered global writes.
__global__ __launch_bounds__(A_THREADS) void range_kernel(
    const int2* __restrict__ edges, const float* __restrict__ phases,
    const float4* __restrict__ x4,
    const float* __restrict__ W1, const float* __restrict__ b1,
    const float* __restrict__ Wout, const float* __restrict__ bout,
    float* __restrict__ part) {
    __shared__ float bins[C_RANGE];
    __shared__ float kc[18];
    const int tid = threadIdx.x;
    const int r = blockIdx.x / N_SLICES;
    const int s = blockIdx.x % N_SLICES;

    compute_consts(W1, b1, Wout, bout, kc, tid);
    for (int j = tid; j < C_RANGE; j += A_THREADS) bins[j] = 0.0f;
    __syncthreads();

    const float c0 = kc[0], c1 = kc[1], c2 = kc[2], c3 = kc[3], cb = kc[4];
    const float a0 = kc[5], a1 = kc[6], a2 = kc[7], a3 = kc[8];
    const float g0 = kc[9], g1 = kc[10], g2 = kc[11], g3 = kc[12];
    const float b10 = kc[13], b11 = kc[14], w0 = kc[15], w1 = kc[16];

    const int nlo = r * C_RANGE;
    const int e0 = s * ES;
    const int e1 = min(e0 + ES, N_EDGES);

    for (int e = e0 + tid; e < e1; e += A_THREADS) {
        int2 ed = edges[e];
        unsigned ju = (unsigned)(ed.x - nlo);   // in-range iff < C_RANGE
        unsigned jv = (unsigned)(ed.y - nlo);
        if (ju < C_RANGE || jv < C_RANGE) {
            float ph = phases[e];
            float sn, cs;
            __sincosf(ph, &sn, &cs);
            if (jv < C_RANGE) {                 // message u -> v lands on node v
                float4 xu = x4[ed.x];
                float h0 = xu.x * a0 + xu.y * a1 + xu.z * a2 + xu.w * a3 + b10;
                float h1 = xu.x * g0 + xu.y * g1 + xu.z * g2 + xu.w * g3 + b11;
                float d  = xu.x * c0 + xu.y * c1 + xu.z * c2 + xu.w * c3 + cb;
                float a  = h0 * w0 + h1 * w1;
                float b  = h0 * w1 - h1 * w0;
                atomicAdd(&bins[jv], cs * a + sn * b + (d - a));
            }
            if (ju < C_RANGE) {                 // message v -> u lands on node u
                float4 xv = x4[ed.y];
                float h0 = xv.x * a0 + xv.y * a1 + xv.z * a2 + xv.w * a3 + b10;
                float h1 = xv.x * g0 + xv.y * g1 + xv.z * g2 + xv.w * g3 + b11;
                float d  = xv.x * c0 + xv.y * c1 + xv.z * c2 + xv.w * c3 + cb;
                float a  = h0 * w0 + h1 * w1;
                float b  = h0 * w1 - h1 * w0;
                atomicAdd(&bins[ju], cs * a - sn * b + (d - a));
            }
        }
    }
    __syncthreads();

    float* __restrict__ dst = part + (size_t)blockIdx.x * C_RANGE;
    for (int j = tid; j < C_RANGE; j += A_THREADS) dst[j] = bins[j];
}

// ---- Kernel B: out[i] = sum_s part[(r,s)][j] + x_i.(W1@Wout) + b1.Wout + bout
__global__ __launch_bounds__(A_THREADS) void reduce_kernel(
    const float4* __restrict__ x4,
    const float* __restrict__ W1, const float* __restrict__ b1,
    const float* __restrict__ Wout, const float* __restrict__ bout,
    const float* __restrict__ part, float* __restrict__ out) {
    __shared__ float kc[18];
    compute_consts(W1, b1, Wout, bout, kc, threadIdx.x);
    __syncthreads();
    int i = blockIdx.x * A_THREADS + threadIdx.x;
    if (i >= N_NODES) return;
    int r = i / C_RANGE;                 // compile-time magic-mul
    int j = i - r * C_RANGE;
    const float* __restrict__ p = part + (size_t)r * N_SLICES * C_RANGE + j;
    float sum = 0.0f;
    #pragma unroll 8
    for (int s = 0; s < N_SLICES; s++) sum += p[(size_t)s * C_RANGE];
    float4 xi = x4[i];
    out[i] = sum + xi.x * kc[0] + xi.y * kc[1] + xi.z * kc[2] + xi.w * kc[3]
           + kc[4] + kc[17];
}

// ---- Fallback (ws too small): direct device atomics ----------------------
__global__ void precompute_kernel(const float* __restrict__ W1,
                                  const float* __restrict__ b1,
                                  const float* __restrict__ Wout,
                                  const float* __restrict__ bout,
                                  float* __restrict__ consts) {
    __shared__ float kc[18];
    compute_consts(W1, b1, Wout, bout, kc, threadIdx.x);
    __syncthreads();
    if (threadIdx.x < 18) consts[threadIdx.x] = kc[threadIdx.x];
}

__global__ void edge_atomic_kernel(const int2* __restrict__ edges,
                                   const float* __restrict__ phases,
                                   const float4* __restrict__ x4,
                                   const float* __restrict__ consts,
                                   float* __restrict__ rep) {
    int e = blockIdx.x * blockDim.x + threadIdx.x;
    if (e >= N_EDGES) return;
    float c0 = consts[0], c1 = consts[1], c2 = consts[2], c3 = consts[3];
    float cb = consts[4];
    float a0 = consts[5], a1 = consts[6], a2 = consts[7], a3 = consts[8];
    float g0 = consts[9], g1 = consts[10], g2 = consts[11], g3 = consts[12];
    float b10 = consts[13], b11 = consts[14], w0 = consts[15], w1 = consts[16];
    int2 ed = edges[e];
    float ph = phases[e];
    float sn, cs;
    __sincosf(ph, &sn, &cs);
    float4 xu = x4[ed.x];
    float4 xv = x4[ed.y];
    float h0u = xu.x * a0 + xu.y * a1 + xu.z * a2 + xu.w * a3 + b10;
    float h1u = xu.x * g0 + xu.y * g1 + xu.z * g2 + xu.w * g3 + b11;
    float du  = xu.x * c0 + xu.y * c1 + xu.z * c2 + xu.w * c3 + cb;
    float au = h0u * w0 + h1u * w1;
    float bu = h0u * w1 - h1u * w0;
    float h0v = xv.x * a0 + xv.y * a1 + xv.z * a2 + xv.w * a3 + b10;
    float h1v = xv.x * g0 + xv.y * g1 + xv.z * g2 + xv.w * g3 + b11;
    float dv  = xv.x * c0 + xv.y * c1 + xv.z * c2 + xv.w * c3 + cb;
    float av = h0v * w0 + h1v * w1;
    float bv = h0v * w1 - h1v * w0;
    atomicAdd(rep + ed.y, cs * au + sn * bu + (du - au));
    atomicAdd(rep + ed.x, cs * av - sn * bv + (dv - av));
}

__global__ void final_kernel(const float4* __restrict__ x4,
                             const float* __restrict__ consts,
                             const float* __restrict__ rep,
                             float* __restrict__ out) {
    int i = blockIdx.x * blockDim.x + threadIdx.x;
    if (i >= N_NODES) return;
    float4 xi = x4[i];
    out[i] = rep[i] + xi.x * consts[0] + xi.y * consts[1] + xi.z * consts[2]
           + xi.w * consts[3] + consts[4] + consts[17];
}

extern "C" void kernel_launch(void* const* d_in, const int* in_sizes, int n_in,
                              void* d_out, int out_size, void* d_ws, size_t ws_size,
                              hipStream_t stream) {
    const float* x      = (const float*)d_in[0];
    const int*   edges  = (const int*)d_in[1];
    const float* W1     = (const float*)d_in[2];
    const float* b1     = (const float*)d_in[3];
    const float* phases = (const float*)d_in[4];
    const float* Wout   = (const float*)d_in[5];
    const float* bout   = (const float*)d_in[6];
    float* out = (float*)d_out;

    const size_t part_bytes = (size_t)N_RANGES * N_SLICES * C_RANGE * sizeof(float); // ~25.7 MB

    if (ws_size >= part_bytes) {
        float* part = (float*)d_ws;
        // No memset needed: every part slot is written by exactly one block.
        range_kernel<<<N_RANGES * N_SLICES, A_THREADS, 0, stream>>>(
            (const int2*)edges, phases, (const float4*)x,
            W1, b1, Wout, bout, part);
        reduce_kernel<<<(N_NODES + A_THREADS - 1) / A_THREADS, A_THREADS, 0, stream>>>(
            (const float4*)x, W1, b1, Wout, bout, part, out);
    } else {
        float* consts = (float*)d_ws;
        float* rep    = (float*)((char*)d_ws + 256);
        hipMemsetAsync(rep, 0, N_NODES * sizeof(float), stream);
        precompute_kernel<<<1, 64, 0, stream>>>(W1, b1, Wout, bout, consts);
        edge_atomic_kernel<<<(N_EDGES + 255) / 256, 256, 0, stream>>>(
            (const int2*)edges, phases, (const float4*)x, consts, rep);
        final_kernel<<<(N_NODES + 255) / 256, 256, 0, stream>>>(
            (const float4*)x, consts, rep, out);
    }
}